// Round 1
// baseline (292.872 us; speedup 1.0000x reference)
//
#include <hip/hip_runtime.h>
#include <cstdint>
#include <cstddef>

// ---------------- types / helpers ----------------
typedef __attribute__((ext_vector_type(8))) __bf16 bf16x8;
typedef __attribute__((ext_vector_type(4))) float  f32x4;

#define MFMA16(a, b, c) __builtin_amdgcn_mfma_f32_16x16x32_bf16((a), (b), (c), 0, 0, 0)

#define T_SEQ 4096
#define NHEADS 8
#define DH 64
#define NEG_INF (-__builtin_huge_valf())
// 1/sqrt(64) * log2(e)  (softmax done in exp2 domain)
#define SCALE_Q 0.18033688011112042f

__device__ __forceinline__ unsigned short f2bf(float f) {
  unsigned int u = __float_as_uint(f);
  u += 0x7fffu + ((u >> 16) & 1u);
  return (unsigned short)(u >> 16);
}

// ---------------- conversion kernels ----------------
__global__ void cvt_x_kernel(const float* __restrict__ x,
                             unsigned short* __restrict__ xb, int n4) {
  int i = blockIdx.x * blockDim.x + threadIdx.x;
  if (i >= n4) return;
  float4 v = ((const float4*)x)[i];
  ushort4 o;
  o.x = f2bf(v.x); o.y = f2bf(v.y); o.z = f2bf(v.z); o.w = f2bf(v.w);
  ((ushort4*)xb)[i] = o;
}

// w [512][N] (K=512 rows) -> wT [N][512] bf16
__global__ void cvt_T_kernel(const float* __restrict__ w,
                             unsigned short* __restrict__ wT, int N, int total) {
  int i = blockIdx.x * blockDim.x + threadIdx.x;
  if (i >= total) return;
  int n = i >> 9, k = i & 511;
  wT[i] = f2bf(w[(size_t)k * N + n]);
}

// ---------------- GEMM: C = A[M,K] * BT[N,K]^T + bias ----------------
// 128x128 block tile, BK=32, 4 waves (each a 64x64 quadrant), 16x16x32 MFMA.
// EPI==0: QKV epilogue (scatter to q/k/v [B*H][T][64] bf16, Q pre-scaled)
// EPI==1: fp32 output [M][512] with bias
template <int EPI>
__global__ __launch_bounds__(256) void gemm_bt(
    const unsigned short* __restrict__ A,
    const unsigned short* __restrict__ BT,
    const float* __restrict__ bias,
    float* __restrict__ outf,
    unsigned short* __restrict__ oq,
    unsigned short* __restrict__ ok,
    unsigned short* __restrict__ ov,
    int K) {
  __shared__ alignas(16) unsigned short As[128 * 32];
  __shared__ alignas(16) unsigned short Bs[128 * 32];

  const int t = threadIdx.x;
  const int lane = t & 63;
  const int w = t >> 6;
  const int wr = (w >> 1) * 64;
  const int wc = (w & 1) * 64;
  const int g = lane >> 4, c = lane & 15;
  const int row0 = blockIdx.y * 128, col0 = blockIdx.x * 128;

  const int crow = t >> 2;          // 0..63
  const int ccol = (t & 3) * 8;     // 0,8,16,24
  const unsigned short* Ag0 = A + (size_t)(row0 + crow) * K + ccol;
  const unsigned short* Ag1 = A + (size_t)(row0 + 64 + crow) * K + ccol;
  const unsigned short* Bg0 = BT + (size_t)(col0 + crow) * K + ccol;
  const unsigned short* Bg1 = BT + (size_t)(col0 + 64 + crow) * K + ccol;

  f32x4 acc[4][4] = {};

  for (int k0 = 0; k0 < K; k0 += 32) {
    int4 a0 = *(const int4*)(Ag0 + k0);
    int4 a1 = *(const int4*)(Ag1 + k0);
    int4 b0 = *(const int4*)(Bg0 + k0);
    int4 b1 = *(const int4*)(Bg1 + k0);
    __syncthreads();
    *(int4*)&As[crow * 32 + ccol] = a0;
    *(int4*)&As[(64 + crow) * 32 + ccol] = a1;
    *(int4*)&Bs[crow * 32 + ccol] = b0;
    *(int4*)&Bs[(64 + crow) * 32 + ccol] = b1;
    __syncthreads();

    bf16x8 af[4], bfr[4];
#pragma unroll
    for (int m = 0; m < 4; ++m)
      af[m] = *(const bf16x8*)&As[(wr + m * 16 + c) * 32 + g * 8];
#pragma unroll
    for (int n = 0; n < 4; ++n)
      bfr[n] = *(const bf16x8*)&Bs[(wc + n * 16 + c) * 32 + g * 8];
#pragma unroll
    for (int m = 0; m < 4; ++m)
#pragma unroll
      for (int n = 0; n < 4; ++n)
        acc[m][n] = MFMA16(af[m], bfr[n], acc[m][n]);
  }

  // epilogue. D layout: row = g*4 + i, col = c (verified m89/m91 mapping)
#pragma unroll
  for (int m = 0; m < 4; ++m) {
#pragma unroll
    for (int n = 0; n < 4; ++n) {
      const int col = col0 + wc + n * 16 + c;
      const float bv = bias[col];
#pragma unroll
      for (int i = 0; i < 4; ++i) {
        const int row = row0 + wr + m * 16 + g * 4 + i;
        float v = acc[m][n][i] + bv;
        if constexpr (EPI == 0) {
          const int which = col >> 9;
          const int h = (col >> 6) & 7;
          const int dh = col & 63;
          const int bb = row >> 12;       // row / T_SEQ
          const int tt = row & 4095;      // row % T_SEQ
          const size_t idx = ((size_t)((bb * NHEADS + h) * T_SEQ + tt)) * DH + dh;
          if (which == 0)      oq[idx] = f2bf(v * SCALE_Q);
          else if (which == 1) ok[idx] = f2bf(v);
          else                 ov[idx] = f2bf(v);
        } else {
          outf[(size_t)row * 512 + col] = v;
        }
      }
    }
  }
}

// ---------------- flash attention (causal) ----------------
// grid (B*H, T/64). 4 waves/block, each wave owns 16 q-rows. KV tiles of 32.
__global__ __launch_bounds__(256) void attn_kernel(
    const unsigned short* __restrict__ qb,
    const unsigned short* __restrict__ kb,
    const unsigned short* __restrict__ vb,
    unsigned short* __restrict__ yb) {
  const int bh = blockIdx.x;
  const int w = threadIdx.x >> 6;
  const int lane = threadIdx.x & 63;
  const int g = lane >> 4, c = lane & 15;
  const int qw0 = blockIdx.y * 64 + w * 16;

  const unsigned short* Qp = qb + (size_t)bh * T_SEQ * DH;
  const unsigned short* Kp = kb + (size_t)bh * T_SEQ * DH;
  const unsigned short* Vp = vb + (size_t)bh * T_SEQ * DH;

  // per-wave P buffer: 16 rows x 32 keys, padded to 40 (bank-conflict-lite,
  // keeps 16B alignment: 40*2=80 bytes/row)
  __shared__ alignas(16) unsigned short Plds[4][16 * 40];

  // Q fragments (A-operand): row = c, k = g*8..g*8+7 (+32 for second frag)
  bf16x8 qf0 = *(const bf16x8*)&Qp[(size_t)(qw0 + c) * DH + g * 8];
  bf16x8 qf1 = *(const bf16x8*)&Qp[(size_t)(qw0 + c) * DH + 32 + g * 8];

  f32x4 acc[4] = {};
  float mi[4] = {NEG_INF, NEG_INF, NEG_INF, NEG_INF};
  float li[4] = {0.f, 0.f, 0.f, 0.f};

  const int jend = qw0 + 15;  // last needed key (inclusive)
  for (int j0 = 0; j0 <= jend; j0 += 32) {
    // S tile: 16 q x 32 keys, two 16-key column sub-tiles
    f32x4 s[2];
#pragma unroll
    for (int ks = 0; ks < 2; ++ks) {
      const unsigned short* Kr = &Kp[(size_t)(j0 + ks * 16 + c) * DH + g * 8];
      bf16x8 kf0 = *(const bf16x8*)Kr;
      bf16x8 kf1 = *(const bf16x8*)(Kr + 32);
      f32x4 z = {0.f, 0.f, 0.f, 0.f};
      z = MFMA16(qf0, kf0, z);
      z = MFMA16(qf1, kf1, z);
      s[ks] = z;
    }

    if (j0 + 31 > qw0) {  // diagonal tile: causal mask
#pragma unroll
      for (int ks = 0; ks < 2; ++ks)
#pragma unroll
        for (int i = 0; i < 4; ++i) {
          const int key = j0 + ks * 16 + c;
          const int qq = qw0 + g * 4 + i;
          if (key > qq) s[ks][i] = NEG_INF;
        }
    }

    // online softmax (exp2 domain; scale folded into Q)
    float mt[4], sc[4];
#pragma unroll
    for (int i = 0; i < 4; ++i) mt[i] = fmaxf(s[0][i], s[1][i]);
#pragma unroll
    for (int off = 1; off < 16; off <<= 1)
#pragma unroll
      for (int i = 0; i < 4; ++i) mt[i] = fmaxf(mt[i], __shfl_xor(mt[i], off));
#pragma unroll
    for (int i = 0; i < 4; ++i) {
      const float mn = fmaxf(mi[i], mt[i]);
      sc[i] = exp2f(mi[i] - mn);
      mi[i] = mn;
    }
    float ls[4] = {0.f, 0.f, 0.f, 0.f};
#pragma unroll
    for (int ks = 0; ks < 2; ++ks)
#pragma unroll
      for (int i = 0; i < 4; ++i) {
        const float p = exp2f(s[ks][i] - mi[i]);
        ls[i] += p;
        Plds[w][(g * 4 + i) * 40 + ks * 16 + c] = f2bf(p);
      }
#pragma unroll
    for (int off = 1; off < 16; off <<= 1)
#pragma unroll
      for (int i = 0; i < 4; ++i) ls[i] += __shfl_xor(ls[i], off);
#pragma unroll
    for (int i = 0; i < 4; ++i) li[i] = li[i] * sc[i] + ls[i];
#pragma unroll
    for (int dt = 0; dt < 4; ++dt)
#pragma unroll
      for (int i = 0; i < 4; ++i) acc[dt][i] *= sc[i];

    // wave-private LDS RAW: make sure writes land before the A-frag read
    asm volatile("s_waitcnt lgkmcnt(0)" ::: "memory");

    // P A-fragment: row = c, k(=key) = g*8..+7
    bf16x8 pf = *(const bf16x8*)&Plds[w][c * 40 + g * 8];

    // PV: V B-operand: V[key = g*8+j][d = dt*16+c] (per-lane gather)
#pragma unroll
    for (int dt = 0; dt < 4; ++dt) {
      union { bf16x8 v; unsigned short u[8]; } uv;
#pragma unroll
      for (int j = 0; j < 8; ++j)
        uv.u[j] = Vp[(size_t)(j0 + g * 8 + j) * DH + dt * 16 + c];
      acc[dt] = MFMA16(pf, uv.v, acc[dt]);
    }
  }

  // normalize + store to y_flat[(b*T + q)*512 + h*64 + d] as bf16
  const int bb = bh >> 3, h = bh & 7;
#pragma unroll
  for (int i = 0; i < 4; ++i) {
    const float inv = 1.0f / li[i];
    const int qq = qw0 + g * 4 + i;
    const size_t base = ((size_t)(bb * T_SEQ + qq)) * 512 + h * DH;
#pragma unroll
    for (int dt = 0; dt < 4; ++dt)
      yb[base + dt * 16 + c] = f2bf(acc[dt][i] * inv);
  }
}

// ---------------- launch ----------------
extern "C" void kernel_launch(void* const* d_in, const int* in_sizes, int n_in,
                              void* d_out, int out_size, void* d_ws, size_t ws_size,
                              hipStream_t stream) {
  const float* x     = (const float*)d_in[0];
  const float* w_qkv = (const float*)d_in[1];
  const float* b_qkv = (const float*)d_in[2];
  const float* w_out = (const float*)d_in[3];
  const float* b_out = (const float*)d_in[4];
  float* out = (float*)d_out;

  char* p = (char*)d_ws;
  unsigned short* xb    = (unsigned short*)p; p += (size_t)8192 * 512 * 2;
  unsigned short* wqkvT = (unsigned short*)p; p += (size_t)1536 * 512 * 2;
  unsigned short* woutT = (unsigned short*)p; p += (size_t)512 * 512 * 2;
  unsigned short* qbuf  = (unsigned short*)p; p += (size_t)16 * T_SEQ * DH * 2;
  unsigned short* kbuf  = (unsigned short*)p; p += (size_t)16 * T_SEQ * DH * 2;
  unsigned short* vbuf  = (unsigned short*)p; p += (size_t)16 * T_SEQ * DH * 2;
  unsigned short* ybuf  = (unsigned short*)p; p += (size_t)8192 * 512 * 2;

  cvt_x_kernel<<<4096, 256, 0, stream>>>(x, xb, 8192 * 512 / 4);
  cvt_T_kernel<<<3072, 256, 0, stream>>>(w_qkv, wqkvT, 1536, 1536 * 512);
  cvt_T_kernel<<<1024, 256, 0, stream>>>(w_out, woutT, 512, 512 * 512);

  // QKV projection: M=8192, N=1536, K=512
  gemm_bt<0><<<dim3(12, 64), 256, 0, stream>>>(xb, wqkvT, b_qkv, nullptr,
                                               qbuf, kbuf, vbuf, 512);
  // attention
  attn_kernel<<<dim3(16, 64), 256, 0, stream>>>(qbuf, kbuf, vbuf, ybuf);
  // output projection: M=8192, N=512, K=512
  gemm_bt<1><<<dim3(4, 64), 256, 0, stream>>>(ybuf, woutT, b_out, out,
                                              nullptr, nullptr, nullptr, 512);
}